// Round 11
// baseline (191.033 us; speedup 1.0000x reference)
//
#include <hip/hip_runtime.h>
#include <hip/hip_bf16.h>
#include <math.h>

#define NN 1024
#define JS 512       // j-slice per block (2 slices), pipelined 32 j at a time
#define NSL 2        // number of slices
#define NCH 16       // chunks of 32 j per block
#define LP 40        // L row pitch (ushorts)

typedef __attribute__((ext_vector_type(8))) short v8s;
typedef __attribute__((ext_vector_type(4))) float v4f;

#define MFMA(a, b, c) __builtin_amdgcn_mfma_f32_16x16x32_bf16((a), (b), (c), 0, 0, 0)

// raw barrier: order LDS only; leave per-wave vmem prefetches in flight
#define BAR() asm volatile("s_waitcnt lgkmcnt(0)\n\ts_barrier" ::: "memory")
#define VM0() asm volatile("s_waitcnt vmcnt(0)" ::: "memory")
// counted wait: retire the 3 staging glls (oldest), keep N expansion
// prefetch loads in flight across the barrier (T4 counted-vmcnt).
#define VMC(N) asm volatile("s_waitcnt vmcnt(" #N ")" ::: "memory")

static __device__ __forceinline__ void gll16(const void* g, void* l) {
    __builtin_amdgcn_global_load_lds(
        (const __attribute__((address_space(1))) unsigned int*)g,
        (__attribute__((address_space(3))) unsigned int*)l, 16, 0, 0);
}

static __device__ __forceinline__ float silu_f(float x) {
    return x / (1.0f + __expf(-x));
}
static __device__ __forceinline__ unsigned short f2bf(float x) {
    __hip_bfloat16 h = __float2bfloat16(x);
    unsigned short u; __builtin_memcpy(&u, &h, 2); return u;
}
static __device__ __forceinline__ unsigned pack2bf(float lo, float hi) {
    __hip_bfloat162 h = __float22bfloat162_rn(make_float2(lo, hi));
    unsigned u; __builtin_memcpy(&u, &h, 4); return u;
}

// ---------------------------------------------------------------------------
// Kernel 1: per-node precompute -> RT[160][1024] bf16 (n-major, j contiguous),
// stored COLUMN-SWIZZLED within each 32-j group: j' = j ^ ((n&3)<<3).
// Edge stages it linearly via global_load_lds and un-swizzles on the MFMA
// B-read (XOR involution): linear dest + pre-swizzled source + swizzled read.
// ---------------------------------------------------------------------------
extern "C" __global__ __launch_bounds__(128)
void node_kernel(const float* __restrict__ scalar,
                 const float* __restrict__ vector,
                 const float* __restrict__ mL_w1, const float* __restrict__ mL_b1,
                 const float* __restrict__ mL_w2, const float* __restrict__ mL_b2,
                 unsigned short* __restrict__ RT)
{
    const int j = blockIdx.x;
    const int t = threadIdx.x;
    __shared__ float ss[32], sh[32], sleft[96];

    if (t < 32) ss[t] = scalar[j * 32 + t];
    __syncthreads();
    if (t < 32) {
        float a = mL_b1[t];
        #pragma unroll
        for (int k = 0; k < 32; k++) a = fmaf(ss[k], mL_w1[k * 32 + t], a);
        sh[t] = silu_f(a);
    }
    __syncthreads();
    if (t < 96) {
        float a = mL_b2[t];
        #pragma unroll
        for (int k = 0; k < 32; k++) a = fmaf(sh[k], mL_w2[k * 96 + t], a);
        sleft[t] = a;
    }
    __syncthreads();
    for (int n = t; n < 160; n += 128) {
        float val;
        if (n < 32)        val = sleft[32 + n];
        else if (n < 128)  val = vector[j * 96 + (n - 32)] * sleft[(n - 32) & 31];
        else               val = sleft[64 + (n - 128)];
        const int jsw = j ^ ((n & 3) << 3);   // swizzle within 32-j group
        RT[(size_t)n * NN + jsw] = f2bf(val);
    }
}

// ---------------------------------------------------------------------------
// Kernel 2: 32-j double-buffered pipeline with COUNTED vmcnt. Per chunk:
// STAGE(c+1 -> other buf) -> pack+MFMA(c) -> vmcnt(N) -> BAR, where N keeps
// the chunk's expansion register-prefetch in flight across the barrier and
// retires only the staging glls. Waves 0/2: T1 (16 acc); 1/3: T2 (8 acc).
// Grid = 1024 = 4 blocks/CU. LDS 38400 B. 64 VGPR + 64 AGPR budget.
// ---------------------------------------------------------------------------
extern "C" __global__ __launch_bounds__(256, 4)
void edge_mfma_kernel(const float* __restrict__ expansion,
                      const float* __restrict__ direction,
                      const float* __restrict__ mask,
                      const float* __restrict__ mR_w, const float* __restrict__ mR_b,
                      const unsigned short* __restrict__ RT,
                      float* __restrict__ part)
{
    const int t = threadIdx.x;
    const int wave = t >> 6;
    const int lane = t & 63;
    const int lrow = lane & 15;
    const int quad = lane >> 4;
    const int jp = lane >> 2;      // 0..15
    const int g  = lane & 3;
    const int jl = jp * 2;

    const int bx = blockIdx.x;
    const int slice = bx & (NSL - 1);
    const int j0 = slice * JS;
    const int iw = wave >> 1;
    const int i = (bx >> 1) * 2 + iw;   // 2 i's per block

    __shared__ __align__(16) unsigned short BSm[2 * 160 * 32];  // 20480 B (2 bufs)
    __shared__ __align__(16) char Wm[13824];                    // pack buffers
    __shared__ __align__(16) float mLds[2 * JS];                // 4096 B

    // STAGE(chunk, bufsel): linear gll of RT[0..159][j0+32c .. +32] into buf.
#define STAGE(C, BSEL)                                                        \
  {                                                                           \
    const unsigned short* s0 =                                                \
        RT + (size_t)(t >> 2) * NN + j0 + (C) * 32 + (t & 3) * 8;             \
    unsigned short* d0 = BSm + (BSEL) * 5120 + t * 8;                         \
    gll16(s0, d0);                                                            \
    gll16(s0 + (size_t)64 * NN, d0 + 2048);                                   \
    if (t < 128) gll16(s0 + (size_t)128 * NN, d0 + 4096);                     \
  }

    // ---- prologue: stage chunk 0 into buf0 + mask rows ----
    STAGE(0, 0);
    for (int q = t; q < 2 * JS; q += 256)
        mLds[q] = mask[(size_t)((bx >> 1) * 2 + (q >> 9)) * NN + j0 + (q & 511)];
    VM0();
    BAR();

    const int kswz = (lrow & 3) << 3;
    const int ko = quad * 8;

    if ((wave & 1) == 0) {
        // ================= T1 wave: rows {m*exp_e (20), m} x B[0..127] ======
        unsigned short* L1 = (unsigned short*)(Wm + iw * 6912);   // [21][LP]
        float* S = (float*)((char*)BSm + iw * 5472);              // [21][65] post-barrier overlay

        v4f acc[16];
        #pragma unroll
        for (int q = 0; q < 16; ++q) acc[q] = (v4f){0.f, 0.f, 0.f, 0.f};

        const float* expA = expansion + ((size_t)i * NN + j0 + jl) * 20;

        float4 fa = *(const float4*)(expA + 4 * g);
        float4 fb = *(const float4*)(expA + 20 + 4 * g);
        float cea = expA[16 + g], ceb = expA[36 + g];
        float2 mc = *(const float2*)(&mLds[iw * JS + jl]);

#define T1_CHUNK(C, BB)                                                       \
  {                                                                           \
    { /* pack */                                                              \
      const float ea[4] = {fa.x, fa.y, fa.z, fa.w};                           \
      const float eb[4] = {fb.x, fb.y, fb.z, fb.w};                           \
      _Pragma("unroll")                                                       \
      for (int k = 0; k < 4; ++k)                                             \
        *(unsigned*)(L1 + (4 * g + k) * LP + jl) =                            \
            pack2bf(mc.x * ea[k], mc.y * eb[k]);                              \
      *(unsigned*)(L1 + (16 + g) * LP + jl) = pack2bf(mc.x * cea, mc.y * ceb);\
      if (g == 0) *(unsigned*)(L1 + 20 * LP + jl) = pack2bf(mc.x, mc.y);      \
    }                                                                         \
    { /* prefetch next chunk (1-deep): exactly 4 loads */                     \
      const int un = ((C) < NCH - 1) ? (C) + 1 : NCH - 1;                     \
      fa = *(const float4*)(expA + un * 640 + 4 * g);                         \
      fb = *(const float4*)(expA + un * 640 + 20 + 4 * g);                    \
      cea = expA[un * 640 + 16 + g];                                          \
      ceb = expA[un * 640 + 36 + g];                                          \
      mc = *(const float2*)(&mLds[iw * JS + un * 32 + jl]);                   \
    }                                                                         \
    { /* MFMA (LDS only, swizzled B) */                                       \
      const v8s a0 = *(const v8s*)(L1 + lrow * LP + ko);                      \
      const v8s a1 = *(const v8s*)(L1 + (16 + lrow) * LP + ko);               \
      const int klz = ko ^ kswz;                                              \
      _Pragma("unroll")                                                       \
      for (int nt = 0; nt < 8; ++nt) {                                        \
        const v8s b = *(const v8s*)((BB) + (nt * 16 + lrow) * 32 + klz);      \
        acc[nt]     = MFMA(a0, b, acc[nt]);                                   \
        acc[8 + nt] = MFMA(a1, b, acc[8 + nt]);                               \
      }                                                                       \
    }                                                                         \
  }

        for (int cc = 0; cc < 8; ++cc) {
            const int c0 = cc * 2;
            STAGE(c0 + 1, 1);                 // next chunk -> buf1
            T1_CHUNK(c0, BSm);                // compute from buf0
            VMC(4); BAR();                    // retire glls; keep 4 prefetch loads
            if (cc < 7) STAGE(c0 + 2, 0);     // next-next -> buf0
            T1_CHUNK(c0 + 1, BSm + 5120);     // compute from buf1
            VMC(4); BAR();
        }
#undef T1_CHUNK

        // epilogue: cols 0..127 of part row (S overlays BSm; post-barrier safe)
        float* pdst = part + ((size_t)i * NSL + slice) * 224;
        #pragma unroll
        for (int h = 0; h < 2; ++h) {
            #pragma unroll
            for (int mt = 0; mt < 2; ++mt)
            #pragma unroll
            for (int q = 0; q < 4; ++q)
            #pragma unroll
            for (int r = 0; r < 4; ++r) {
                const int row = mt * 16 + quad * 4 + r;
                if (row <= 20) S[row * 65 + q * 16 + lrow] = acc[mt * 8 + h * 4 + q][r];
            }
            const int col = h * 64 + lane;
            const int fw = (col < 32) ? (32 + col) : ((col - 32) & 31);
            float v = mR_b[fw] * S[20 * 65 + lane];
            #pragma unroll
            for (int e = 0; e < 20; ++e)
                v = fmaf(mR_w[e * 96 + fw], S[e * 65 + lane], v);
            pdst[col] = v;
        }
    } else {
        // ========== T2 wave: rows {m*dir_d*exp_e (60), m*dir_d (3)} x B[128..159]
        unsigned short* L2 = (unsigned short*)(Wm + 1792 + iw * 6912); // [63][LP]
        float* S = (float*)((char*)BSm + 10944 + iw * 4288);           // [63][17] post-barrier overlay

        v4f acc[8];
        #pragma unroll
        for (int q = 0; q < 8; ++q) acc[q] = (v4f){0.f, 0.f, 0.f, 0.f};

        const float* expA = expansion + ((size_t)i * NN + j0 + jl) * 20;
        const float* dirA = direction + ((size_t)i * NN + j0 + jl) * 3;

        float4 fa = *(const float4*)(expA + 4 * g);
        float4 fb = *(const float4*)(expA + 20 + 4 * g);
        float cea = expA[16 + g], ceb = expA[36 + g];
        float2 mc = *(const float2*)(&mLds[iw * JS + jl]);
        float2 dv0 = *(const float2*)(dirA);        // da0, da1
        float2 dv1 = *(const float2*)(dirA + 2);    // da2, db0
        float2 dv2 = *(const float2*)(dirA + 4);    // db1, db2

#define T2_CHUNK(C, BB)                                                       \
  {                                                                           \
    { /* pack */                                                              \
      const float pa[3] = {mc.x * dv0.x, mc.x * dv0.y, mc.x * dv1.x};         \
      const float pb[3] = {mc.y * dv1.y, mc.y * dv2.x, mc.y * dv2.y};         \
      const float ea[4] = {fa.x, fa.y, fa.z, fa.w};                           \
      const float eb[4] = {fb.x, fb.y, fb.z, fb.w};                           \
      _Pragma("unroll")                                                       \
      for (int d = 0; d < 3; ++d) {                                           \
        _Pragma("unroll")                                                     \
        for (int k = 0; k < 4; ++k)                                           \
          *(unsigned*)(L2 + (d * 20 + 4 * g + k) * LP + jl) =                 \
              pack2bf(pa[d] * ea[k], pb[d] * eb[k]);                          \
        *(unsigned*)(L2 + (d * 20 + 16 + g) * LP + jl) =                      \
            pack2bf(pa[d] * cea, pb[d] * ceb);                                \
      }                                                                       \
      if (g == 0) {                                                           \
        *(unsigned*)(L2 + (60 + 0) * LP + jl) = pack2bf(pa[0], pb[0]);        \
        *(unsigned*)(L2 + (60 + 1) * LP + jl) = pack2bf(pa[1], pb[1]);        \
        *(unsigned*)(L2 + (60 + 2) * LP + jl) = pack2bf(pa[2], pb[2]);        \
      }                                                                       \
    }                                                                         \
    { /* prefetch next chunk (1-deep): >=5 loads (4 certain + dv merged >=1) */\
      const int un = ((C) < NCH - 1) ? (C) + 1 : NCH - 1;                     \
      fa = *(const float4*)(expA + un * 640 + 4 * g);                         \
      fb = *(const float4*)(expA + un * 640 + 20 + 4 * g);                    \
      cea = expA[un * 640 + 16 + g];                                          \
      ceb = expA[un * 640 + 36 + g];                                          \
      dv0 = *(const float2*)(dirA + un * 96);                                 \
      dv1 = *(const float2*)(dirA + un * 96 + 2);                             \
      dv2 = *(const float2*)(dirA + un * 96 + 4);                             \
      mc = *(const float2*)(&mLds[iw * JS + un * 32 + jl]);                   \
    }                                                                         \
    { /* MFMA (LDS only, swizzled B) */                                       \
      const v8s c0 = *(const v8s*)(L2 + (lrow) * LP + ko);                    \
      const v8s c1 = *(const v8s*)(L2 + (16 + lrow) * LP + ko);               \
      const v8s c2 = *(const v8s*)(L2 + (32 + lrow) * LP + ko);               \
      const v8s c3 = *(const v8s*)(L2 + (48 + lrow) * LP + ko);               \
      const int klz = ko ^ kswz;                                              \
      const v8s b0 = *(const v8s*)((BB) + (128 + lrow) * 32 + klz);           \
      const v8s b1 = *(const v8s*)((BB) + (144 + lrow) * 32 + klz);           \
      acc[0] = MFMA(c0, b0, acc[0]); acc[1] = MFMA(c0, b1, acc[1]);           \
      acc[2] = MFMA(c1, b0, acc[2]); acc[3] = MFMA(c1, b1, acc[3]);           \
      acc[4] = MFMA(c2, b0, acc[4]); acc[5] = MFMA(c2, b1, acc[5]);           \
      acc[6] = MFMA(c3, b0, acc[6]); acc[7] = MFMA(c3, b1, acc[7]);           \
    }                                                                         \
  }

        for (int cc = 0; cc < 8; ++cc) {
            const int c0 = cc * 2;
            STAGE(c0 + 1, 1);                 // next chunk -> buf1
            T2_CHUNK(c0, BSm);                // compute from buf0
            VMC(5); BAR();                    // retire glls; keep >=5 prefetch loads
            if (cc < 7) STAGE(c0 + 2, 0);     // next-next -> buf0
            T2_CHUNK(c0 + 1, BSm + 5120);     // compute from buf1
            VMC(5); BAR();
        }
#undef T2_CHUNK

        // epilogue: cols 128..223 of part row (S overlays BSm)
        float* pdst = part + ((size_t)i * NSL + slice) * 224;
        #pragma unroll
        for (int h2 = 0; h2 < 2; ++h2) {
            #pragma unroll
            for (int mt = 0; mt < 4; ++mt)
            #pragma unroll
            for (int r = 0; r < 4; ++r) {
                const int row = mt * 16 + quad * 4 + r;
                if (row <= 62) S[row * 17 + lrow] = acc[mt * 2 + h2][r];
            }
            if (lane < 48) {
                const int dd = lane >> 4, f16 = lane & 15;
                const int f = h2 * 16 + f16;
                float v = mR_b[64 + f] * S[(60 + dd) * 17 + f16];
                #pragma unroll
                for (int e = 0; e < 20; ++e)
                    v = fmaf(mR_w[e * 96 + 64 + f], S[(dd * 20 + e) * 17 + f16], v);
                pdst[128 + dd * 32 + f] = v;
            }
        }
    }
#undef STAGE
}

// ---------------------------------------------------------------------------
// Kernel 3: sum 2 slice-partials + update phase, one block per row.
// ---------------------------------------------------------------------------
extern "C" __global__ __launch_bounds__(256)
void combine_kernel(const float* __restrict__ scalar,
                    const float* __restrict__ vector,
                    const float* __restrict__ uR_w1, const float* __restrict__ uR_b1,
                    const float* __restrict__ uR_w2, const float* __restrict__ uR_b2,
                    const float* __restrict__ U_w,  const float* __restrict__ V_w,
                    const float* __restrict__ part,
                    float* __restrict__ out)
{
    const int i = blockIdx.x;
    const int t = threadIdx.x;
    __shared__ float pcomb[224];
    __shared__ float snew[32], vnew[96];
    __shared__ float lU[96], rV[96], rnorm[32], h2[32], f2[96];

    if (t < 224) {
        const float* p = part + (size_t)i * NSL * 224 + t;
        float a = 0.f;
        #pragma unroll
        for (int s = 0; s < NSL; ++s) a += p[s * 224];
        pcomb[t] = a;
    }
    __syncthreads();

    if (t < 128) {
        const int d = t >> 5, ff = t & 31;
        if (d == 0) snew[ff] = scalar[i * 32 + ff] + pcomb[ff];
        else {
            const int q = t - 32;
            vnew[q] = vector[i * 96 + q] + pcomb[32 + q] + pcomb[128 + q];
        }
    }
    __syncthreads();

    if (t < 96) {
        const int d = t >> 5, ff = t & 31;
        float a = 0.0f;
        #pragma unroll
        for (int k = 0; k < 32; k++) a = fmaf(vnew[d * 32 + k], U_w[k * 32 + ff], a);
        lU[t] = a;
    } else if (t >= 128 && t < 224) {
        const int dt = t - 128, d = dt >> 5, ff = dt & 31;
        float a = 0.0f;
        #pragma unroll
        for (int k = 0; k < 32; k++) a = fmaf(vnew[d * 32 + k], V_w[k * 32 + ff], a);
        rV[dt] = a;
    }
    __syncthreads();
    if (t < 32) {
        const float a = rV[t] * rV[t] + rV[32 + t] * rV[32 + t] + rV[64 + t] * rV[64 + t];
        rnorm[t] = sqrtf(a);
    }
    __syncthreads();
    if (t < 32) {
        float a = uR_b1[t];
        #pragma unroll
        for (int k = 0; k < 32; k++) a = fmaf(snew[k],  uR_w1[k * 32 + t], a);
        #pragma unroll
        for (int k = 0; k < 32; k++) a = fmaf(rnorm[k], uR_w1[(32 + k) * 32 + t], a);
        h2[t] = silu_f(a);
    }
    __syncthreads();
    if (t < 96) {
        float a = uR_b2[t];
        #pragma unroll
        for (int k = 0; k < 32; k++) a = fmaf(h2[k], uR_w2[k * 96 + t], a);
        f2[t] = a;
    }
    __syncthreads();
    if (t < 32) {
        const float inner = lU[t] * rV[t] + lU[32 + t] * rV[32 + t] + lU[64 + t] * rV[64 + t];
        out[i * 32 + t] = snew[t] + inner * f2[32 + t] + f2[64 + t];
    } else if (t >= 64 && t < 160) {
        const int dt = t - 64, ff = dt & 31;
        out[32768 + i * 96 + dt] = vnew[dt] + f2[ff] * lU[dt];
    }
}

extern "C" void kernel_launch(void* const* d_in, const int* in_sizes, int n_in,
                              void* d_out, int out_size, void* d_ws, size_t ws_size,
                              hipStream_t stream) {
    const float* scalar    = (const float*)d_in[0];
    const float* vector    = (const float*)d_in[1];
    const float* expansion = (const float*)d_in[2];
    const float* direction = (const float*)d_in[3];
    const float* mask      = (const float*)d_in[4];
    const float* mL_w1     = (const float*)d_in[5];
    const float* mL_b1     = (const float*)d_in[6];
    const float* mL_w2     = (const float*)d_in[7];
    const float* mL_b2     = (const float*)d_in[8];
    const float* mR_w      = (const float*)d_in[9];
    const float* mR_b      = (const float*)d_in[10];
    const float* uR_w1     = (const float*)d_in[11];
    const float* uR_b1     = (const float*)d_in[12];
    const float* uR_w2     = (const float*)d_in[13];
    const float* uR_b2     = (const float*)d_in[14];
    const float* U_w       = (const float*)d_in[15];
    const float* V_w       = (const float*)d_in[16];
    float* out = (float*)d_out;

    unsigned short* RT = (unsigned short*)d_ws;                 // 320 KB
    float* part = (float*)((char*)d_ws + 160 * NN * 2);         // 1024*2*224*4 = 1.83 MB

    hipLaunchKernelGGL(node_kernel, dim3(NN), dim3(128), 0, stream,
                       scalar, vector, mL_w1, mL_b1, mL_w2, mL_b2, RT);
    hipLaunchKernelGGL(edge_mfma_kernel, dim3(NN), dim3(256), 0, stream,
                       expansion, direction, mask, mR_w, mR_b, RT, part);
    hipLaunchKernelGGL(combine_kernel, dim3(NN), dim3(256), 0, stream,
                       scalar, vector, uR_w1, uR_b1, uR_w2, uR_b2, U_w, V_w,
                       part, out);
}

// Round 12
// 185.893 us; speedup vs baseline: 1.0276x; 1.0276x over previous
//
#include <hip/hip_runtime.h>
#include <hip/hip_bf16.h>
#include <math.h>

#define NN 1024
#define JS 512       // j-slice per block (2 slices), staged 64 j at a time
#define NSL 2        // number of slices
#define LP 40        // L row pitch (ushorts)

typedef __attribute__((ext_vector_type(8))) short v8s;
typedef __attribute__((ext_vector_type(4))) float v4f;

#define MFMA(a, b, c) __builtin_amdgcn_mfma_f32_16x16x32_bf16((a), (b), (c), 0, 0, 0)

// raw barrier: order LDS only; leave per-wave vmem prefetches in flight
#define BAR() asm volatile("s_waitcnt lgkmcnt(0)\n\ts_barrier" ::: "memory")
#define VM0() asm volatile("s_waitcnt vmcnt(0)" ::: "memory")

static __device__ __forceinline__ void gll16(const void* g, void* l) {
    __builtin_amdgcn_global_load_lds(
        (const __attribute__((address_space(1))) unsigned int*)g,
        (__attribute__((address_space(3))) unsigned int*)l, 16, 0, 0);
}

static __device__ __forceinline__ float silu_f(float x) {
    return x / (1.0f + __expf(-x));
}
static __device__ __forceinline__ unsigned short f2bf(float x) {
    __hip_bfloat16 h = __float2bfloat16(x);
    unsigned short u; __builtin_memcpy(&u, &h, 2); return u;
}
static __device__ __forceinline__ unsigned pack2bf(float lo, float hi) {
    __hip_bfloat162 h = __float22bfloat162_rn(make_float2(lo, hi));
    unsigned u; __builtin_memcpy(&u, &h, 4); return u;
}

// ---------------------------------------------------------------------------
// Kernel 1: per-node precompute -> RT[160][1024] bf16 (n-major, j contiguous),
// stored COLUMN-SWIZZLED within each 64-j group: j' = j ^ ((n&7)<<3).
// Edge stages it linearly via global_load_lds and un-swizzles on the MFMA
// B-read (XOR involution): linear dest + pre-swizzled source + swizzled read.
// ---------------------------------------------------------------------------
extern "C" __global__ __launch_bounds__(128)
void node_kernel(const float* __restrict__ scalar,
                 const float* __restrict__ vector,
                 const float* __restrict__ mL_w1, const float* __restrict__ mL_b1,
                 const float* __restrict__ mL_w2, const float* __restrict__ mL_b2,
                 unsigned short* __restrict__ RT)
{
    const int j = blockIdx.x;
    const int t = threadIdx.x;
    __shared__ float ss[32], sh[32], sleft[96];

    if (t < 32) ss[t] = scalar[j * 32 + t];
    __syncthreads();
    if (t < 32) {
        float a = mL_b1[t];
        #pragma unroll
        for (int k = 0; k < 32; k++) a = fmaf(ss[k], mL_w1[k * 32 + t], a);
        sh[t] = silu_f(a);
    }
    __syncthreads();
    if (t < 96) {
        float a = mL_b2[t];
        #pragma unroll
        for (int k = 0; k < 32; k++) a = fmaf(sh[k], mL_w2[k * 96 + t], a);
        sleft[t] = a;
    }
    __syncthreads();
    for (int n = t; n < 160; n += 128) {
        float val;
        if (n < 32)        val = sleft[32 + n];
        else if (n < 128)  val = vector[j * 96 + (n - 32)] * sleft[(n - 32) & 31];
        else               val = sleft[64 + (n - 128)];
        const int jsw = j ^ ((n & 7) << 3);   // swizzle within 64-j group
        RT[(size_t)n * NN + jsw] = f2bf(val);
    }
}

// ---------------------------------------------------------------------------
// Kernel 2: best-known configuration (round 9). NSL=2 / JS=512.
// Grid = 1024 blocks = 4 blocks/CU x 256 CU -> full single-round residency.
// Waves 0/2: T1 (16 acc) for i0/i1; waves 1/3: T2 (8 acc).
// gll staging, mask-in-LDS, swizzled linear B-tile; 1-deep prefetch
// (64 VGPR + 64 AGPR budget, proven). LDS 38400 B -> 4 blocks/CU.
// ---------------------------------------------------------------------------
extern "C" __global__ __launch_bounds__(256, 4)
void edge_mfma_kernel(const float* __restrict__ expansion,
                      const float* __restrict__ direction,
                      const float* __restrict__ mask,
                      const float* __restrict__ mR_w, const float* __restrict__ mR_b,
                      const unsigned short* __restrict__ RT,
                      float* __restrict__ part)
{
    const int t = threadIdx.x;
    const int wave = t >> 6;
    const int lane = t & 63;
    const int lrow = lane & 15;
    const int quad = lane >> 4;
    const int jp = lane >> 2;      // 0..15
    const int g  = lane & 3;
    const int jl = jp * 2;

    const int bx = blockIdx.x;
    const int slice = bx & (NSL - 1);
    const int j0 = slice * JS;
    const int iw = wave >> 1;
    const int i = (bx >> 1) * 2 + iw;   // 2 i's per block

    __shared__ __align__(16) unsigned short BSm[160 * 64];   // 20480 B
    __shared__ __align__(16) char Wm[13824];                 // pack buffers
    __shared__ __align__(16) float mLds[2 * JS];             // 4096 B

    // staging bases (linear LDS dest = wave-uniform base + lane*16)
    const unsigned short* rtbase = RT + ((size_t)(t >> 3) * NN) + ((t & 7) * 8) + j0;
    unsigned short* lds_dst = BSm + t * 8;

    // ---- prologue: stage sub-tile 0 + mask rows ----
    #pragma unroll
    for (int k = 0; k < 5; ++k)
        gll16(rtbase + (size_t)k * 32 * NN, lds_dst + k * 2048);
    for (int q = t; q < 2 * JS; q += 256)
        mLds[q] = mask[(size_t)((bx >> 1) * 2 + (q >> 9)) * NN + j0 + (q & 511)];
    VM0();
    BAR();

    const int kswz = (lrow & 7) << 3;
    const int ko = quad * 8;

    if ((wave & 1) == 0) {
        // ================= T1 wave: rows {m*exp_e (20), m} x B[0..127] ======
        unsigned short* L1 = (unsigned short*)(Wm + iw * 6912);   // [21][LP]
        float* S = (float*)((char*)BSm + iw * 5472);              // [21][65] post-barrier overlay

        v4f acc[16];
        #pragma unroll
        for (int q = 0; q < 16; ++q) acc[q] = (v4f){0.f, 0.f, 0.f, 0.f};

        const float* expA = expansion + ((size_t)i * NN + j0 + jl) * 20;

        float4 fa = *(const float4*)(expA + 4 * g);
        float4 fb = *(const float4*)(expA + 20 + 4 * g);
        float cea = expA[16 + g], ceb = expA[36 + g];
        float2 mc = *(const float2*)(&mLds[iw * JS + jl]);

        for (int ss2 = 0; ss2 < 8; ++ss2) {
            #pragma unroll
            for (int ch = 0; ch < 2; ++ch) {
                // pack current chunk
                {
                    const float ea[4] = {fa.x, fa.y, fa.z, fa.w};
                    const float eb[4] = {fb.x, fb.y, fb.z, fb.w};
                    #pragma unroll
                    for (int k = 0; k < 4; ++k)
                        *(unsigned*)(L1 + (4 * g + k) * LP + jl) =
                            pack2bf(mc.x * ea[k], mc.y * eb[k]);
                    *(unsigned*)(L1 + (16 + g) * LP + jl) = pack2bf(mc.x * cea, mc.y * ceb);
                    if (g == 0) *(unsigned*)(L1 + 20 * LP + jl) = pack2bf(mc.x, mc.y);
                }
                // prefetch next chunk (1-deep)
                {
                    const int u = ss2 * 2 + ch;
                    const int un = (u < 15) ? u + 1 : 15;
                    fa = *(const float4*)(expA + un * 640 + 4 * g);
                    fb = *(const float4*)(expA + un * 640 + 20 + 4 * g);
                    cea = expA[un * 640 + 16 + g];
                    ceb = expA[un * 640 + 36 + g];
                    mc = *(const float2*)(&mLds[iw * JS + un * 32 + jl]);
                }
                // MFMA (LDS only, swizzled B)
                {
                    const v8s a0 = *(const v8s*)(L1 + lrow * LP + ko);
                    const v8s a1 = *(const v8s*)(L1 + (16 + lrow) * LP + ko);
                    const int klz = (ch * 32 + ko) ^ kswz;
                    #pragma unroll
                    for (int nt = 0; nt < 8; ++nt) {
                        const v8s b = *(const v8s*)(BSm + (nt * 16 + lrow) * 64 + klz);
                        acc[nt]     = MFMA(a0, b, acc[nt]);
                        acc[8 + nt] = MFMA(a1, b, acc[8 + nt]);
                    }
                }
            }
            BAR();                               // all waves done reading BSm
            if (ss2 < 7) {
                const unsigned short* src = rtbase + (ss2 + 1) * 64;
                #pragma unroll
                for (int k = 0; k < 5; ++k)
                    gll16(src + (size_t)k * 32 * NN, lds_dst + k * 2048);
                VM0();
                BAR();                           // next sub-tile visible
            }
        }

        // epilogue: cols 0..127 of part row (S overlays BSm; post-barrier safe)
        float* pdst = part + ((size_t)i * NSL + slice) * 224;
        #pragma unroll
        for (int h = 0; h < 2; ++h) {
            #pragma unroll
            for (int mt = 0; mt < 2; ++mt)
            #pragma unroll
            for (int q = 0; q < 4; ++q)
            #pragma unroll
            for (int r = 0; r < 4; ++r) {
                const int row = mt * 16 + quad * 4 + r;
                if (row <= 20) S[row * 65 + q * 16 + lrow] = acc[mt * 8 + h * 4 + q][r];
            }
            const int col = h * 64 + lane;
            const int fw = (col < 32) ? (32 + col) : ((col - 32) & 31);
            float v = mR_b[fw] * S[20 * 65 + lane];
            #pragma unroll
            for (int e = 0; e < 20; ++e)
                v = fmaf(mR_w[e * 96 + fw], S[e * 65 + lane], v);
            pdst[col] = v;
        }
    } else {
        // ========== T2 wave: rows {m*dir_d*exp_e (60), m*dir_d (3)} x B[128..159]
        unsigned short* L2 = (unsigned short*)(Wm + 1792 + iw * 6912); // [63][LP]
        float* S = (float*)((char*)BSm + 10944 + iw * 4288);           // [63][17] post-barrier overlay

        v4f acc[8];
        #pragma unroll
        for (int q = 0; q < 8; ++q) acc[q] = (v4f){0.f, 0.f, 0.f, 0.f};

        const float* expA = expansion + ((size_t)i * NN + j0 + jl) * 20;
        const float* dirA = direction + ((size_t)i * NN + j0 + jl) * 3;

        float4 fa = *(const float4*)(expA + 4 * g);
        float4 fb = *(const float4*)(expA + 20 + 4 * g);
        float cea = expA[16 + g], ceb = expA[36 + g];
        float2 mc = *(const float2*)(&mLds[iw * JS + jl]);
        float2 dv0 = *(const float2*)(dirA);        // da0, da1
        float2 dv1 = *(const float2*)(dirA + 2);    // da2, db0
        float2 dv2 = *(const float2*)(dirA + 4);    // db1, db2

        for (int ss2 = 0; ss2 < 8; ++ss2) {
            #pragma unroll
            for (int ch = 0; ch < 2; ++ch) {
                // pack current chunk
                {
                    const float pa[3] = {mc.x * dv0.x, mc.x * dv0.y, mc.x * dv1.x};
                    const float pb[3] = {mc.y * dv1.y, mc.y * dv2.x, mc.y * dv2.y};
                    const float ea[4] = {fa.x, fa.y, fa.z, fa.w};
                    const float eb[4] = {fb.x, fb.y, fb.z, fb.w};
                    #pragma unroll
                    for (int d = 0; d < 3; ++d) {
                        #pragma unroll
                        for (int k = 0; k < 4; ++k)
                            *(unsigned*)(L2 + (d * 20 + 4 * g + k) * LP + jl) =
                                pack2bf(pa[d] * ea[k], pb[d] * eb[k]);
                        *(unsigned*)(L2 + (d * 20 + 16 + g) * LP + jl) =
                            pack2bf(pa[d] * cea, pb[d] * ceb);
                    }
                    if (g == 0) {
                        *(unsigned*)(L2 + (60 + 0) * LP + jl) = pack2bf(pa[0], pb[0]);
                        *(unsigned*)(L2 + (60 + 1) * LP + jl) = pack2bf(pa[1], pb[1]);
                        *(unsigned*)(L2 + (60 + 2) * LP + jl) = pack2bf(pa[2], pb[2]);
                    }
                }
                // prefetch next chunk (1-deep)
                {
                    const int u = ss2 * 2 + ch;
                    const int un = (u < 15) ? u + 1 : 15;
                    fa = *(const float4*)(expA + un * 640 + 4 * g);
                    fb = *(const float4*)(expA + un * 640 + 20 + 4 * g);
                    cea = expA[un * 640 + 16 + g];
                    ceb = expA[un * 640 + 36 + g];
                    dv0 = *(const float2*)(dirA + un * 96);
                    dv1 = *(const float2*)(dirA + un * 96 + 2);
                    dv2 = *(const float2*)(dirA + un * 96 + 4);
                    mc = *(const float2*)(&mLds[iw * JS + un * 32 + jl]);
                }
                // MFMA (LDS only, swizzled B)
                {
                    const v8s c0 = *(const v8s*)(L2 + (lrow) * LP + ko);
                    const v8s c1 = *(const v8s*)(L2 + (16 + lrow) * LP + ko);
                    const v8s c2 = *(const v8s*)(L2 + (32 + lrow) * LP + ko);
                    const v8s c3 = *(const v8s*)(L2 + (48 + lrow) * LP + ko);
                    const int klz = (ch * 32 + ko) ^ kswz;
                    const v8s b0 = *(const v8s*)(BSm + (128 + lrow) * 64 + klz);
                    const v8s b1 = *(const v8s*)(BSm + (144 + lrow) * 64 + klz);
                    acc[0] = MFMA(c0, b0, acc[0]); acc[1] = MFMA(c0, b1, acc[1]);
                    acc[2] = MFMA(c1, b0, acc[2]); acc[3] = MFMA(c1, b1, acc[3]);
                    acc[4] = MFMA(c2, b0, acc[4]); acc[5] = MFMA(c2, b1, acc[5]);
                    acc[6] = MFMA(c3, b0, acc[6]); acc[7] = MFMA(c3, b1, acc[7]);
                }
            }
            BAR();                               // all waves done reading BSm
            if (ss2 < 7) {
                const unsigned short* src = rtbase + (ss2 + 1) * 64;
                #pragma unroll
                for (int k = 0; k < 5; ++k)
                    gll16(src + (size_t)k * 32 * NN, lds_dst + k * 2048);
                VM0();
                BAR();                           // next sub-tile visible
            }
        }

        // epilogue: cols 128..223 of part row (S overlays BSm)
        float* pdst = part + ((size_t)i * NSL + slice) * 224;
        #pragma unroll
        for (int h2 = 0; h2 < 2; ++h2) {
            #pragma unroll
            for (int mt = 0; mt < 4; ++mt)
            #pragma unroll
            for (int r = 0; r < 4; ++r) {
                const int row = mt * 16 + quad * 4 + r;
                if (row <= 62) S[row * 17 + lrow] = acc[mt * 2 + h2][r];
            }
            if (lane < 48) {
                const int dd = lane >> 4, f16 = lane & 15;
                const int f = h2 * 16 + f16;
                float v = mR_b[64 + f] * S[(60 + dd) * 17 + f16];
                #pragma unroll
                for (int e = 0; e < 20; ++e)
                    v = fmaf(mR_w[e * 96 + 64 + f], S[(dd * 20 + e) * 17 + f16], v);
                pdst[128 + dd * 32 + f] = v;
            }
        }
    }
}

// ---------------------------------------------------------------------------
// Kernel 3: sum 2 slice-partials + update phase, one block per row.
// ---------------------------------------------------------------------------
extern "C" __global__ __launch_bounds__(256)
void combine_kernel(const float* __restrict__ scalar,
                    const float* __restrict__ vector,
                    const float* __restrict__ uR_w1, const float* __restrict__ uR_b1,
                    const float* __restrict__ uR_w2, const float* __restrict__ uR_b2,
                    const float* __restrict__ U_w,  const float* __restrict__ V_w,
                    const float* __restrict__ part,
                    float* __restrict__ out)
{
    const int i = blockIdx.x;
    const int t = threadIdx.x;
    __shared__ float pcomb[224];
    __shared__ float snew[32], vnew[96];
    __shared__ float lU[96], rV[96], rnorm[32], h2[32], f2[96];

    if (t < 224) {
        const float* p = part + (size_t)i * NSL * 224 + t;
        float a = 0.f;
        #pragma unroll
        for (int s = 0; s < NSL; ++s) a += p[s * 224];
        pcomb[t] = a;
    }
    __syncthreads();

    if (t < 128) {
        const int d = t >> 5, ff = t & 31;
        if (d == 0) snew[ff] = scalar[i * 32 + ff] + pcomb[ff];
        else {
            const int q = t - 32;
            vnew[q] = vector[i * 96 + q] + pcomb[32 + q] + pcomb[128 + q];
        }
    }
    __syncthreads();

    if (t < 96) {
        const int d = t >> 5, ff = t & 31;
        float a = 0.0f;
        #pragma unroll
        for (int k = 0; k < 32; k++) a = fmaf(vnew[d * 32 + k], U_w[k * 32 + ff], a);
        lU[t] = a;
    } else if (t >= 128 && t < 224) {
        const int dt = t - 128, d = dt >> 5, ff = dt & 31;
        float a = 0.0f;
        #pragma unroll
        for (int k = 0; k < 32; k++) a = fmaf(vnew[d * 32 + k], V_w[k * 32 + ff], a);
        rV[dt] = a;
    }
    __syncthreads();
    if (t < 32) {
        const float a = rV[t] * rV[t] + rV[32 + t] * rV[32 + t] + rV[64 + t] * rV[64 + t];
        rnorm[t] = sqrtf(a);
    }
    __syncthreads();
    if (t < 32) {
        float a = uR_b1[t];
        #pragma unroll
        for (int k = 0; k < 32; k++) a = fmaf(snew[k],  uR_w1[k * 32 + t], a);
        #pragma unroll
        for (int k = 0; k < 32; k++) a = fmaf(rnorm[k], uR_w1[(32 + k) * 32 + t], a);
        h2[t] = silu_f(a);
    }
    __syncthreads();
    if (t < 96) {
        float a = uR_b2[t];
        #pragma unroll
        for (int k = 0; k < 32; k++) a = fmaf(h2[k], uR_w2[k * 96 + t], a);
        f2[t] = a;
    }
    __syncthreads();
    if (t < 32) {
        const float inner = lU[t] * rV[t] + lU[32 + t] * rV[32 + t] + lU[64 + t] * rV[64 + t];
        out[i * 32 + t] = snew[t] + inner * f2[32 + t] + f2[64 + t];
    } else if (t >= 64 && t < 160) {
        const int dt = t - 64, ff = dt & 31;
        out[32768 + i * 96 + dt] = vnew[dt] + f2[ff] * lU[dt];
    }
}

extern "C" void kernel_launch(void* const* d_in, const int* in_sizes, int n_in,
                              void* d_out, int out_size, void* d_ws, size_t ws_size,
                              hipStream_t stream) {
    const float* scalar    = (const float*)d_in[0];
    const float* vector    = (const float*)d_in[1];
    const float* expansion = (const float*)d_in[2];
    const float* direction = (const float*)d_in[3];
    const float* mask      = (const float*)d_in[4];
    const float* mL_w1     = (const float*)d_in[5];
    const float* mL_b1     = (const float*)d_in[6];
    const float* mL_w2     = (const float*)d_in[7];
    const float* mL_b2     = (const float*)d_in[8];
    const float* mR_w      = (const float*)d_in[9];
    const float* mR_b      = (const float*)d_in[10];
    const float* uR_w1     = (const float*)d_in[11];
    const float* uR_b1     = (const float*)d_in[12];
    const float* uR_w2     = (const float*)d_in[13];
    const float* uR_b2     = (const float*)d_in[14];
    const float* U_w       = (const float*)d_in[15];
    const float* V_w       = (const float*)d_in[16];
    float* out = (float*)d_out;

    unsigned short* RT = (unsigned short*)d_ws;                 // 320 KB
    float* part = (float*)((char*)d_ws + 160 * NN * 2);         // 1024*2*224*4 = 1.83 MB

    hipLaunchKernelGGL(node_kernel, dim3(NN), dim3(128), 0, stream,
                       scalar, vector, mL_w1, mL_b1, mL_w2, mL_b2, RT);
    hipLaunchKernelGGL(edge_mfma_kernel, dim3(NN), dim3(256), 0, stream,
                       expansion, direction, mask, mR_w, mR_b, RT, part);
    hipLaunchKernelGGL(combine_kernel, dim3(NN), dim3(256), 0, stream,
                       scalar, vector, uR_w1, uR_b1, uR_w2, uR_b2, U_w, V_w,
                       part, out);
}